// Round 2
// baseline (685.486 us; speedup 1.0000x reference)
//
#include <hip/hip_runtime.h>
#include <math.h>

#define B_    8
#define CIN_  64
#define COUT_ 64
#define Hs    96
#define Ws    96
#define KK    9
#define PLANE (Hs*Ws)        // 9216
#define IMG   (CIN_*PLANE)   // 589824
#define NP    (B_*PLANE)     // 73728
#define NBLK  (NP/64)        // 1152 blocks

// XCD-contiguous swizzle: round-robin dispatch -> contiguous 144-block chunk per XCD
__device__ __forceinline__ int swz(int bid) { return (bid & 7) * (NBLK / 8) + (bid >> 3); }

// Transposed weights for scalar-load access:
//   wT[(k*64+c)*64+o]  = weight[o*576 + c*9 + k]   (36864 floats)
//   woT[(c*27+ch)*9+t] = w_off[ch*576 + c*9 + t]   (15552 floats)
__global__ void transpose_weights(const float* __restrict__ weight,
                                  const float* __restrict__ w_off,
                                  float* __restrict__ wT,
                                  float* __restrict__ woT) {
    int i = blockIdx.x * 256 + threadIdx.x;
    if (i < COUT_ * CIN_ * KK) {
        int o = i & 63;
        int c = (i >> 6) & 63;
        int k = i >> 12;
        wT[i] = weight[o * 576 + c * 9 + k];
    }
    if (i < 27 * CIN_ * KK) {
        int t  = i % 9;
        int ch = (i / 9) % 27;
        int c  = i / (27 * 9);
        woT[i] = w_off[ch * 576 + c * 9 + t];
    }
}

// ---------------- Kernel A: offset conv 64->27, pad=1 ----------------
// block: 64 pixels x 4 cin-groups (16 cin each). Planar output om[27][NP].
__global__ __launch_bounds__(256)
void offset_conv(const float* __restrict__ x,
                 const float* __restrict__ woT,
                 const float* __restrict__ b_off,
                 float* __restrict__ om) {
    __shared__ float part[256 * 27];   // 27.6 KB
    int tid = threadIdx.x;
    int px  = tid & 63;
    int cg  = tid >> 6;                 // wave id = cin group
    int pg  = swz(blockIdx.x) * 64 + px;
    int b = pg / PLANE;
    int r = pg - b * PLANE;
    int h = r / Ws;
    int w = r - h * Ws;
    const float* xb = x + b * IMG + cg * 16 * PLANE;

    // precompute clamped neighbor offsets + validity masks (per pixel)
    int   off[9];
    float msk[9];
#pragma unroll
    for (int i = 0; i < 3; ++i) {
        int yy = h - 1 + i;
        int yc = min(max(yy, 0), Hs - 1);
        bool vy = (yy >= 0) && (yy < Hs);
#pragma unroll
        for (int j = 0; j < 3; ++j) {
            int xx = w - 1 + j;
            int xc = min(max(xx, 0), Ws - 1);
            bool v = vy && (xx >= 0) && (xx < Ws);
            off[i * 3 + j] = yc * Ws + xc;
            msk[i * 3 + j] = v ? 1.f : 0.f;
        }
    }

    float o27[27];
#pragma unroll
    for (int ch = 0; ch < 27; ++ch) o27[ch] = 0.f;

#pragma unroll 1
    for (int cc = 0; cc < 16; ++cc) {
        const float* xp = xb + cc * PLANE;
        float xv[9];
#pragma unroll
        for (int t = 0; t < 9; ++t) xv[t] = xp[off[t]] * msk[t];
        const float* wc = woT + (cg * 16 + cc) * 243;   // wave-uniform -> s_loads
#pragma unroll
        for (int ch = 0; ch < 27; ++ch) {
#pragma unroll
            for (int t = 0; t < 9; ++t)
                o27[ch] = fmaf(xv[t], wc[ch * 9 + t], o27[ch]);
        }
    }

#pragma unroll
    for (int ch = 0; ch < 27; ++ch) part[tid * 27 + ch] = o27[ch];
    __syncthreads();

    for (int ch = cg; ch < 27; ch += 4) {
        float s = b_off[ch];
#pragma unroll
        for (int g = 0; g < 4; ++g) s += part[(px + 64 * g) * 27 + ch];
        om[ch * NP + pg] = s;   // planar, coalesced
    }
}

// ---------------- Kernel B: sampling + main conv ----------------
// block: 64 pixels x 4 groups. Per tap: waves cooperatively stage
// sampled[c][px] (16 KB LDS), then each wave FMAs its 16 output channels.
__global__ __launch_bounds__(256)
void deform_main(const float* __restrict__ x,
                 const float* __restrict__ om,    // [27][NP]
                 const float* __restrict__ wT,    // [k][c][o]
                 const float* __restrict__ bias,
                 float* __restrict__ out) {
    __shared__ float smp[64 * 64];   // 16 KB: [c][px]
    int tid = threadIdx.x;
    int px  = tid & 63;
    int g   = tid >> 6;              // wave id: cin-group (stage) / oc-group (fma)
    int pg  = swz(blockIdx.x) * 64 + px;
    int b = pg / PLANE;
    int r = pg - b * PLANE;
    int h = r / Ws;
    int w = r - h * Ws;
    const float* xb = x + b * IMG;

    float acc[16];
#pragma unroll
    for (int o = 0; o < 16; ++o) acc[o] = bias[g * 16 + o];

#pragma unroll 1
    for (int k = 0; k < KK; ++k) {
        float dy = om[(2 * k) * NP + pg];
        float dx = om[(2 * k + 1) * NP + pg];
        float mo = om[(18 + k) * NP + pg];
        float m  = 1.f / (1.f + expf(-mo));

        float ys = (float)(h - 1 + k / 3) + dy;
        float xs = (float)(w - 1 + k % 3) + dx;
        float y0f = floorf(ys), x0f = floorf(xs);
        float ly = ys - y0f, lx = xs - x0f;
        float hy = 1.f - ly, hx = 1.f - lx;
        int y0 = (int)y0f, x0 = (int)x0f;
        int y1 = y0 + 1,  x1 = x0 + 1;
        bool vy0 = (y0 >= 0) && (y0 < Hs);
        bool vy1 = (y1 >= 0) && (y1 < Hs);
        bool vx0 = (x0 >= 0) && (x0 < Ws);
        bool vx1 = (x1 >= 0) && (x1 < Ws);
        float w00 = (vy0 && vx0) ? m * hy * hx : 0.f;
        float w01 = (vy0 && vx1) ? m * hy * lx : 0.f;
        float w10 = (vy1 && vx0) ? m * ly * hx : 0.f;
        float w11 = (vy1 && vx1) ? m * ly * lx : 0.f;
        int y0c = min(max(y0, 0), Hs - 1), y1c = min(max(y1, 0), Hs - 1);
        int x0c = min(max(x0, 0), Ws - 1), x1c = min(max(x1, 0), Ws - 1);
        int o00 = y0c * Ws + x0c, o01 = y0c * Ws + x1c;
        int o10 = y1c * Ws + x0c, o11 = y1c * Ws + x1c;

        __syncthreads();   // previous tap's FMA stage done before overwrite
        const float* xg = xb + g * 16 * PLANE;
#pragma unroll
        for (int i = 0; i < 16; ++i) {
            const float* xp = xg + i * PLANE;
            float v = xp[o00] * w00 + xp[o01] * w01 + xp[o10] * w10 + xp[o11] * w11;
            smp[(g * 16 + i) * 64 + px] = v;   // lane=px consecutive: conflict-free
        }
        __syncthreads();

        const float* wk = wT + k * (CIN_ * COUT_) + g * 16;
#pragma unroll 4
        for (int c = 0; c < 64; ++c) {
            float s = smp[c * 64 + px];
            const float* wc = wk + c * COUT_;   // wave-uniform -> s_loads
#pragma unroll
            for (int o = 0; o < 16; ++o)
                acc[o] = fmaf(s, wc[o], acc[o]);
        }
    }

    int obase = b * (COUT_ * PLANE) + r + (g * 16) * PLANE;
#pragma unroll
    for (int o = 0; o < 16; ++o)
        out[obase + o * PLANE] = acc[o];   // lane=px consecutive: coalesced
}

extern "C" void kernel_launch(void* const* d_in, const int* in_sizes, int n_in,
                              void* d_out, int out_size, void* d_ws, size_t ws_size,
                              hipStream_t stream) {
    const float* x      = (const float*)d_in[0];
    const float* w_off  = (const float*)d_in[1];
    const float* b_off  = (const float*)d_in[2];
    const float* weight = (const float*)d_in[3];
    const float* bias   = (const float*)d_in[4];
    float* out = (float*)d_out;

    char* ws = (char*)d_ws;
    float* wT  = (float*)ws;                 // 147456 B
    float* woT = (float*)(ws + 0x24000);     //  62208 B
    float* omb = (float*)(ws + 0x40000);     // 27*73728*4 = 7.96 MB

    transpose_weights<<<144, 256, 0, stream>>>(weight, w_off, wT, woT);
    offset_conv<<<NBLK, 256, 0, stream>>>(x, woT, b_off, omb);
    deform_main<<<NBLK, 256, 0, stream>>>(x, omb, wT, bias, out);
}

// Round 3
// 271.331 us; speedup vs baseline: 2.5264x; 2.5264x over previous
//
#include <hip/hip_runtime.h>
#include <math.h>

#define B_    8
#define CIN_  64
#define COUT_ 64
#define Hs    96
#define Ws    96
#define KK    9
#define PLANE (Hs*Ws)        // 9216
#define IMG   (CIN_*PLANE)   // 589824
#define NP    (B_*PLANE)     // 73728
#define NBLK  (NP/64)        // 1152 blocks

// XCD-contiguous swizzle: round-robin dispatch -> contiguous 144-block chunk per XCD
__device__ __forceinline__ int swz(int bid) { return (bid & 7) * (NBLK / 8) + (bid >> 3); }

// Transposed weights for scalar-load access:
//   wT[(k*64+c)*64+o]  = weight[o*576 + c*9 + k]   (36864 floats)
//   woT[(c*27+ch)*9+t] = w_off[ch*576 + c*9 + t]   (15552 floats)
__global__ void transpose_weights(const float* __restrict__ weight,
                                  const float* __restrict__ w_off,
                                  float* __restrict__ wT,
                                  float* __restrict__ woT) {
    int i = blockIdx.x * 256 + threadIdx.x;
    if (i < COUT_ * CIN_ * KK) {
        int o = i & 63;
        int c = (i >> 6) & 63;
        int k = i >> 12;
        wT[i] = weight[o * 576 + c * 9 + k];
    }
    if (i < 27 * CIN_ * KK) {
        int t  = i % 9;
        int ch = (i / 9) % 27;
        int c  = i / (27 * 9);
        woT[i] = w_off[ch * 576 + c * 9 + t];
    }
}

// ---------------- Kernel A: offset conv 64->27, pad=1 ----------------
// block: 64 pixels x 4 cin-groups (16 cin each). Planar output om[27][NP].
__global__ __launch_bounds__(256)
void offset_conv(const float* __restrict__ x,
                 const float* __restrict__ woT,
                 const float* __restrict__ b_off,
                 float* __restrict__ om) {
    __shared__ float part[256 * 27];   // 27.6 KB
    int tid = threadIdx.x;
    int px  = tid & 63;
    // wave id: wave-uniform -> force into SGPR so weight addrs become s_loads
    int cg  = __builtin_amdgcn_readfirstlane(tid >> 6);
    int pg  = swz(blockIdx.x) * 64 + px;
    int b = pg / PLANE;
    int r = pg - b * PLANE;
    int h = r / Ws;
    int w = r - h * Ws;
    const float* xb = x + b * IMG + cg * 16 * PLANE;

    // precompute clamped neighbor offsets + validity masks (per pixel)
    int   off[9];
    float msk[9];
#pragma unroll
    for (int i = 0; i < 3; ++i) {
        int yy = h - 1 + i;
        int yc = min(max(yy, 0), Hs - 1);
        bool vy = (yy >= 0) && (yy < Hs);
#pragma unroll
        for (int j = 0; j < 3; ++j) {
            int xx = w - 1 + j;
            int xc = min(max(xx, 0), Ws - 1);
            bool v = vy && (xx >= 0) && (xx < Ws);
            off[i * 3 + j] = yc * Ws + xc;
            msk[i * 3 + j] = v ? 1.f : 0.f;
        }
    }

    float o27[27];
#pragma unroll
    for (int ch = 0; ch < 27; ++ch) o27[ch] = 0.f;

#pragma unroll 1
    for (int cc = 0; cc < 16; ++cc) {
        const float* xp = xb + cc * PLANE;
        float xv[9];
#pragma unroll
        for (int t = 0; t < 9; ++t) xv[t] = xp[off[t]] * msk[t];
        const float* wc = woT + (cg * 16 + cc) * 243;   // SGPR base -> s_loads
#pragma unroll
        for (int ch = 0; ch < 27; ++ch) {
#pragma unroll
            for (int t = 0; t < 9; ++t)
                o27[ch] = fmaf(xv[t], wc[ch * 9 + t], o27[ch]);
        }
    }

#pragma unroll
    for (int ch = 0; ch < 27; ++ch) part[tid * 27 + ch] = o27[ch];
    __syncthreads();

    for (int ch = cg; ch < 27; ch += 4) {
        float s = b_off[ch];
#pragma unroll
        for (int g = 0; g < 4; ++g) s += part[(px + 64 * g) * 27 + ch];
        om[ch * NP + pg] = s;   // planar, coalesced
    }
}

// ---------------- Kernel B: sampling + main conv ----------------
// block: 64 pixels x 4 waves. Per tap: waves cooperatively stage
// sampled[c][px] (16 KB LDS), then each wave FMAs its 16 output channels
// with weights from SCALAR loads (wave-uniform address via readfirstlane).
__global__ __launch_bounds__(256)
void deform_main(const float* __restrict__ x,
                 const float* __restrict__ om,    // [27][NP]
                 const float* __restrict__ wT,    // [k][c][o]
                 const float* __restrict__ bias,
                 float* __restrict__ out) {
    __shared__ float smp[64 * 64];   // 16 KB: [c][px]
    int tid = threadIdx.x;
    int px  = tid & 63;
    int g   = __builtin_amdgcn_readfirstlane(tid >> 6);  // wave-uniform -> SGPR
    int pg  = swz(blockIdx.x) * 64 + px;
    int b = pg / PLANE;
    int r = pg - b * PLANE;
    int h = r / Ws;
    int w = r - h * Ws;
    const float* xb = x + b * IMG;

    float acc[16];
#pragma unroll
    for (int o = 0; o < 16; ++o) acc[o] = bias[g * 16 + o];

#pragma unroll 1
    for (int k = 0; k < KK; ++k) {
        float dy = om[(2 * k) * NP + pg];
        float dx = om[(2 * k + 1) * NP + pg];
        float mo = om[(18 + k) * NP + pg];
        float m  = 1.f / (1.f + expf(-mo));

        float ys = (float)(h - 1 + k / 3) + dy;
        float xs = (float)(w - 1 + k % 3) + dx;
        float y0f = floorf(ys), x0f = floorf(xs);
        float ly = ys - y0f, lx = xs - x0f;
        float hy = 1.f - ly, hx = 1.f - lx;
        int y0 = (int)y0f, x0 = (int)x0f;
        int y1 = y0 + 1,  x1 = x0 + 1;
        bool vy0 = (y0 >= 0) && (y0 < Hs);
        bool vy1 = (y1 >= 0) && (y1 < Hs);
        bool vx0 = (x0 >= 0) && (x0 < Ws);
        bool vx1 = (x1 >= 0) && (x1 < Ws);
        float w00 = (vy0 && vx0) ? m * hy * hx : 0.f;
        float w01 = (vy0 && vx1) ? m * hy * lx : 0.f;
        float w10 = (vy1 && vx0) ? m * ly * hx : 0.f;
        float w11 = (vy1 && vx1) ? m * ly * lx : 0.f;
        int y0c = min(max(y0, 0), Hs - 1), y1c = min(max(y1, 0), Hs - 1);
        int x0c = min(max(x0, 0), Ws - 1), x1c = min(max(x1, 0), Ws - 1);
        int o00 = y0c * Ws + x0c, o01 = y0c * Ws + x1c;
        int o10 = y1c * Ws + x0c, o11 = y1c * Ws + x1c;

        __syncthreads();   // previous tap's FMA stage done before overwrite
        const float* xg = xb + g * 16 * PLANE;
#pragma unroll
        for (int i = 0; i < 16; ++i) {
            const float* xp = xg + i * PLANE;
            float v = xp[o00] * w00 + xp[o01] * w01 + xp[o10] * w10 + xp[o11] * w11;
            smp[(g * 16 + i) * 64 + px] = v;   // lane=px consecutive: conflict-free
        }
        __syncthreads();

        const float* wk = wT + k * (CIN_ * COUT_) + g * 16;  // SGPR base
#pragma unroll 4
        for (int c = 0; c < 64; ++c) {
            float s = smp[c * 64 + px];
            const float* wc = wk + c * COUT_;   // wave-uniform -> s_load_dwordx16
#pragma unroll
            for (int o = 0; o < 16; ++o)
                acc[o] = fmaf(s, wc[o], acc[o]);
        }
    }

    int obase = b * (COUT_ * PLANE) + r + (g * 16) * PLANE;
#pragma unroll
    for (int o = 0; o < 16; ++o)
        out[obase + o * PLANE] = acc[o];   // lane=px consecutive: coalesced
}

extern "C" void kernel_launch(void* const* d_in, const int* in_sizes, int n_in,
                              void* d_out, int out_size, void* d_ws, size_t ws_size,
                              hipStream_t stream) {
    const float* x      = (const float*)d_in[0];
    const float* w_off  = (const float*)d_in[1];
    const float* b_off  = (const float*)d_in[2];
    const float* weight = (const float*)d_in[3];
    const float* bias   = (const float*)d_in[4];
    float* out = (float*)d_out;

    char* ws = (char*)d_ws;
    float* wT  = (float*)ws;                 // 147456 B
    float* woT = (float*)(ws + 0x24000);     //  62208 B
    float* omb = (float*)(ws + 0x40000);     // 27*73728*4 = 7.96 MB

    transpose_weights<<<144, 256, 0, stream>>>(weight, w_off, wT, woT);
    offset_conv<<<NBLK, 256, 0, stream>>>(x, woT, b_off, omb);
    deform_main<<<NBLK, 256, 0, stream>>>(x, omb, wT, bias, out);
}